// Round 6
// baseline (2374.122 us; speedup 1.0000x reference)
//
#include <hip/hip_runtime.h>

#define B 4096
#define T 2048
#define H 64
#define NBATCH 16
#define NB (B / NBATCH)     // 256 blocks, 1 per CU
#define NTHREADS 1024       // 16 waves -> 4 waves/SIMD, 1 cell/lane

typedef __attribute__((ext_vector_type(8))) short short8;
typedef __attribute__((ext_vector_type(4))) float f32x4;

__device__ __forceinline__ float rcp_(float x) { return __builtin_amdgcn_rcpf(x); }
__device__ __forceinline__ float ex2(float x) { return __builtin_amdgcn_exp2f(x); }
__device__ __forceinline__ float sigm_exact(float x) {        // mid_kernel only
    return rcp_(1.0f + ex2(-1.4426950408889634f * x));
}
// (5,4) Pade tanh, clamp +-3.5: max err ~1.1e-3. No exp2 -- FMA chain + rcp.
__device__ __forceinline__ float tanh_pade(float x) {
    float xc = fminf(3.5f, fmaxf(-3.5f, x));
    float x2 = xc * xc;
    float num = xc * (945.0f + x2 * (105.0f + x2));
    float q   = 945.0f + x2 * (420.0f + 15.0f * x2);
    return num * rcp_(q);
}
__device__ __forceinline__ unsigned short f2bf(float f) {     // RNE f32->bf16
    unsigned u = __builtin_bit_cast(unsigned, f);
    u += 0x7fffu + ((u >> 16) & 1u);
    return (unsigned short)(u >> 16);
}
// LDS-only barrier: drain lgkm (ds ops) but leave global loads in flight.
__device__ __forceinline__ void lds_barrier() {
    asm volatile("s_waitcnt lgkmcnt(0)\n\ts_barrier" ::: "memory");
}

// Gate math: acc0..3 -> i,f,g,o with 3 rcp total (pairwise-combined for the
// 4 gates' Pade denominators) + Pade tail for tanh(cn).
// sigma(x) = 0.5 + 0.5*tanh(x/2).
#define GATES(ACC0, ACC1, ACC2, ACC3, CST, CN, HN)                            \
    float a0 = 0.5f * (ACC0), a1 = 0.5f * (ACC1), a2 = (ACC2), a3 = 0.5f * (ACC3); \
    a0 = fminf(3.5f, fmaxf(-3.5f, a0)); a1 = fminf(3.5f, fmaxf(-3.5f, a1));   \
    a2 = fminf(3.5f, fmaxf(-3.5f, a2)); a3 = fminf(3.5f, fmaxf(-3.5f, a3));   \
    float s0 = a0 * a0, s1 = a1 * a1, s2 = a2 * a2, s3 = a3 * a3;             \
    float n0 = a0 * (945.0f + s0 * (105.0f + s0));                            \
    float n1 = a1 * (945.0f + s1 * (105.0f + s1));                            \
    float n2 = a2 * (945.0f + s2 * (105.0f + s2));                            \
    float n3 = a3 * (945.0f + s3 * (105.0f + s3));                            \
    float q0 = 945.0f + s0 * (420.0f + 15.0f * s0);                           \
    float q1 = 945.0f + s1 * (420.0f + 15.0f * s1);                           \
    float q2 = 945.0f + s2 * (420.0f + 15.0f * s2);                           \
    float q3 = 945.0f + s3 * (420.0f + 15.0f * s3);                           \
    float r01 = rcp_(q0 * q1), r23 = rcp_(q2 * q3);                           \
    float i_ = fmaf(0.5f, n0 * (q1 * r01), 0.5f);                             \
    float f_ = fmaf(0.5f, n1 * (q0 * r01), 0.5f);                             \
    float g_ = n2 * (q3 * r23);                                               \
    float o_ = fmaf(0.5f, n3 * (q2 * r23), 0.5f);                             \
    float CN = f_ * (CST) + i_ * g_;                                          \
    float HN = o_ * tanh_pade(CN);

// ---------------------------------------------------------------------------
// Encoder: 256 blocks x 1024 threads (16 waves), 16 batches/block, 1 cell/lane.
// Wave w owns units w*4..w*4+3 via remapped A rows: G(m) = (m&3)*64+w*4+(m>>2).
// C row hi*4+r = gate r of unit w*4+hi, col = batch lo. Two INDEPENDENT
// K-half MFMAs summed (breaks serial MFMA dep).
// ---------------------------------------------------------------------------
extern "C" __global__ void __launch_bounds__(NTHREADS, 1)
enc_kernel(const float* __restrict__ padded, const int* __restrict__ seq_len,
           const float* __restrict__ Wih, const float* __restrict__ Whh,
           const float* __restrict__ bias,
           float* __restrict__ h_out, float* __restrict__ c_out)
{
    __shared__ unsigned short hA[2][NBATCH][72];
    __shared__ int slen[NBATCH];

    const int tid = threadIdx.x;
    const int w = tid >> 6, L = tid & 63, lo = L & 15, hi = L >> 4;
    const int b0 = blockIdx.x * NBATCH;
    const int unit = w * 4 + hi;

    short8 af[2];
    {
        const int G = (lo & 3) * 64 + w * 4 + (lo >> 2);
        #pragma unroll
        for (int kk = 0; kk < 2; ++kk) {
            const float* src = Whh + (long)G * H + kk * 32 + hi * 8;
            short8 f;
            #pragma unroll
            for (int j = 0; j < 8; ++j) f[j] = (short)f2bf(src[j]);
            af[kk] = f;
        }
    }
    float b_g[4], wi_g[4];
    #pragma unroll
    for (int r = 0; r < 4; ++r) {
        const int G2 = r * 64 + unit;
        b_g[r] = bias[G2];
        wi_g[r] = Wih[G2];
    }

    if (tid < NBATCH * 64) hA[0][tid >> 6][tid & 63] = 0;
    if (tid < NBATCH) slen[tid] = seq_len[b0 + tid];
    lds_barrier();

    int maxlen = 1;
    #pragma unroll
    for (int i = 0; i < NBATCH; ++i) maxlen = max(maxlen, slen[i]);
    const int len_lo = slen[lo];

    const float* xrow = padded + (long)(b0 + lo) * T;
    f32x4 xc = *(const f32x4*)(xrow);
    f32x4 xn = *(const f32x4*)(xrow + 4);

    float c_st = 0.f, h_st = 0.f;

#define ESTEP(P, XI)                                                          \
    {                                                                         \
        const float x = xc[XI];                                               \
        short8 hb0 = *(const short8*)&hA[P][lo][hi * 8];                      \
        short8 hb1 = *(const short8*)&hA[P][lo][32 + hi * 8];                 \
        f32x4 z1 = {b_g[0] + wi_g[0] * x, b_g[1] + wi_g[1] * x,               \
                    b_g[2] + wi_g[2] * x, b_g[3] + wi_g[3] * x};              \
        f32x4 z2 = {0.f, 0.f, 0.f, 0.f};                                      \
        z1 = __builtin_amdgcn_mfma_f32_16x16x32_bf16(af[0], hb0, z1, 0,0,0);  \
        z2 = __builtin_amdgcn_mfma_f32_16x16x32_bf16(af[1], hb1, z2, 0,0,0);  \
        const bool act = (t + XI) < len_lo;                                   \
        GATES(z1[0] + z2[0], z1[1] + z2[1], z1[2] + z2[2], z1[3] + z2[3],     \
              c_st, cn, hn)                                                   \
        if (act) { c_st = cn; h_st = hn; }                                    \
        hA[(P) ^ 1][lo][unit] = f2bf(h_st);                                   \
        lds_barrier();                                                        \
    }

    for (int t = 0; t < maxlen; t += 4) {
        int nb = t + 8; if (nb > T - 4) nb = T - 4;
        f32x4 xf = *(const f32x4*)(xrow + nb);   // 8-step-ahead prefetch
        ESTEP(0, 0) ESTEP(1, 1) ESTEP(0, 2) ESTEP(1, 3)
        xc = xn; xn = xf;
    }
#undef ESTEP

    h_out[(long)(b0 + lo) * H + unit] = h_st;
    c_out[(long)(b0 + lo) * H + unit] = c_st;
}

// ---------------------------------------------------------------------------
// Bottleneck (exact sigmoid -- hz is a direct output) + y0 correction term.
// ---------------------------------------------------------------------------
extern "C" __global__ void __launch_bounds__(256)
mid_kernel(const float* __restrict__ h_enc,
           const float* __restrict__ eW, const float* __restrict__ eb,
           const float* __restrict__ dW, const float* __restrict__ db,
           const float* __restrict__ outW, const float* __restrict__ outb,
           float* __restrict__ hz_out, float* __restrict__ hd_out,
           float* __restrict__ y0c)
{
    int b = blockIdx.x * blockDim.x + threadIdx.x;
    if (b >= B) return;
    const float* h = h_enc + (long)b * H;
    float hz[3];
    #pragma unroll
    for (int j = 0; j < 3; ++j) {
        float s = eb[j];
        for (int k = 0; k < H; ++k) s += h[k] * eW[j*H + k];
        hz[j] = sigm_exact(s);
        hz_out[b*3 + j] = hz[j];
    }
    float y0 = outb[0];
    for (int u = 0; u < H; ++u) {
        float hd = db[u] + hz[0]*dW[u*3] + hz[1]*dW[u*3+1] + hz[2]*dW[u*3+2];
        hd_out[(long)b*H + u] = hd;
        y0 += outW[u] * hd;
    }
    y0c[b] = y0;
}

// ---------------------------------------------------------------------------
// Decoder: rank-1 fold (W' = Whh + Wih (x) outW, b' = b + Wih*outb) -> pure
// LSTM. y_{t-1} recovered via 2 extra MFMAs rotating across waves (w==t&15).
// t=0 correction peeled. Same Pade gate math.
// ---------------------------------------------------------------------------
extern "C" __global__ void __launch_bounds__(NTHREADS, 1)
dec_kernel(const float* __restrict__ hd, const float* __restrict__ c_in,
           const float* __restrict__ Wih, const float* __restrict__ Whh,
           const float* __restrict__ bias, const float* __restrict__ outW,
           const float* __restrict__ outb, const float* __restrict__ y0c,
           float* __restrict__ y_out)
{
    __shared__ unsigned short hA[2][NBATCH][72];

    const int tid = threadIdx.x;
    const int w = tid >> 6, L = tid & 63, lo = L & 15, hi = L >> 4;
    const int b0 = blockIdx.x * NBATCH;
    const int unit = w * 4 + hi;

    short8 af[2];
    {
        const int G = (lo & 3) * 64 + w * 4 + (lo >> 2);
        const float wir = Wih[G];
        #pragma unroll
        for (int kk = 0; kk < 2; ++kk) {
            const float* src = Whh + (long)G * H + kk * 32 + hi * 8;
            const float* ow  = outW + kk * 32 + hi * 8;
            short8 f;
            #pragma unroll
            for (int j = 0; j < 8; ++j) f[j] = (short)f2bf(src[j] + wir * ow[j]);
            af[kk] = f;
        }
    }
    const float outb_s = outb[0];
    const float y0 = y0c[b0 + lo];
    float b_g[4], corr[4];
    #pragma unroll
    for (int r = 0; r < 4; ++r) {
        const int G2 = r * 64 + unit;
        const float wir = Wih[G2];
        b_g[r] = bias[G2] + wir * outb_s;
        corr[r] = wir * y0;
    }
    short8 ya[2];   // y-extraction A-frag: row 0 = outW, rows 1..15 = 0
    #pragma unroll
    for (int kk = 0; kk < 2; ++kk) {
        short8 f = (short8)0;
        if (lo == 0)
            #pragma unroll
            for (int j = 0; j < 8; ++j) f[j] = (short)f2bf(outW[kk*32 + hi*8 + j]);
        ya[kk] = f;
    }

    if (tid < NBATCH * 64) {
        int m = tid >> 6, k = tid & 63;
        hA[0][m][k] = f2bf(hd[(long)(b0 + m) * H + k]);
    }
    float c_st = c_in[(long)(b0 + lo) * H + unit];
    lds_barrier();

#define DSTEP(P, CORR, TT)                                                    \
    {                                                                         \
        short8 hb0 = *(const short8*)&hA[P][lo][hi * 8];                      \
        short8 hb1 = *(const short8*)&hA[P][lo][32 + hi * 8];                 \
        f32x4 z1 = {b_g[0], b_g[1], b_g[2], b_g[3]};                          \
        f32x4 z2 = {0.f, 0.f, 0.f, 0.f};                                      \
        z1 = __builtin_amdgcn_mfma_f32_16x16x32_bf16(af[0], hb0, z1, 0,0,0);  \
        z2 = __builtin_amdgcn_mfma_f32_16x16x32_bf16(af[1], hb1, z2, 0,0,0);  \
        if (w == ((TT) & 15)) {  /* y_{t-1} = outW.h_{t-1}+outb, rotated */   \
            f32x4 zy = {outb_s, outb_s, outb_s, outb_s};                      \
            zy = __builtin_amdgcn_mfma_f32_16x16x32_bf16(ya[0], hb0, zy, 0,0,0); \
            zy = __builtin_amdgcn_mfma_f32_16x16x32_bf16(ya[1], hb1, zy, 0,0,0); \
            if ((TT) > 0 && hi == 0)                                          \
                y_out[(long)(b0 + lo) * T + ((TT) - 1)] = zy[0];              \
        }                                                                     \
        float e0 = z1[0] + z2[0], e1 = z1[1] + z2[1];                         \
        float e2 = z1[2] + z2[2], e3 = z1[3] + z2[3];                         \
        if (CORR) { e0 -= corr[0]; e1 -= corr[1]; e2 -= corr[2]; e3 -= corr[3]; } \
        GATES(e0, e1, e2, e3, c_st, cn, hn)                                   \
        c_st = cn;                                                            \
        hA[(P) ^ 1][lo][unit] = f2bf(hn);                                     \
        lds_barrier();                                                        \
    }

    DSTEP(0, 1, 0) DSTEP(1, 0, 1) DSTEP(0, 0, 2) DSTEP(1, 0, 3)
    for (int t = 4; t < T; t += 4) {
        DSTEP(0, 0, t) DSTEP(1, 0, t + 1) DSTEP(0, 0, t + 2) DSTEP(1, 0, t + 3)
    }
#undef DSTEP

    if (w == 0) {       // final y_{T-1} (T even -> parity 0)
        short8 hb0 = *(const short8*)&hA[0][lo][hi * 8];
        short8 hb1 = *(const short8*)&hA[0][lo][32 + hi * 8];
        f32x4 zy = {outb_s, outb_s, outb_s, outb_s};
        zy = __builtin_amdgcn_mfma_f32_16x16x32_bf16(ya[0], hb0, zy, 0,0,0);
        zy = __builtin_amdgcn_mfma_f32_16x16x32_bf16(ya[1], hb1, zy, 0,0,0);
        if (hi == 0) y_out[(long)(b0 + lo) * T + (T - 1)] = zy[0];
    }
}

// ---------------------------------------------------------------------------
extern "C" __global__ void __launch_bounds__(256)
loss_kernel(const float* __restrict__ padded, const float* __restrict__ y,
            const int* __restrict__ seq_len, float* __restrict__ acc2)
{
    const long n4 = (long)B * T / 4;
    long i0 = (long)(blockIdx.x * blockDim.x + threadIdx.x);
    long stride = (long)gridDim.x * blockDim.x;
    float s = 0.f, cnt = 0.f;
    for (long i = i0; i < n4; i += stride) {
        int b = (int)(i >> 9);                  // T/4 = 512
        int t = (int)(i & 511) * 4;
        int len = seq_len[b];
        f32x4 pv = *(const f32x4*)&padded[i * 4];
        f32x4 yv = *(const f32x4*)&y[i * 4];
        #pragma unroll
        for (int e = 0; e < 4; ++e)
            if (t + e < len) { float d = pv[e] - yv[e]; s += d * d; cnt += 1.0f; }
    }
    for (int m = 1; m < 64; m <<= 1) { s += __shfl_xor(s, m); cnt += __shfl_xor(cnt, m); }
    if ((threadIdx.x & 63) == 0) { atomicAdd(&acc2[0], s); atomicAdd(&acc2[1], cnt); }
}

extern "C" __global__ void fin_kernel(const float* __restrict__ acc2, float* __restrict__ out)
{
    out[0] = acc2[0] / acc2[1];
}

// ---------------------------------------------------------------------------
extern "C" void kernel_launch(void* const* d_in, const int* in_sizes, int n_in,
                              void* d_out, int out_size, void* d_ws, size_t ws_size,
                              hipStream_t stream)
{
    const float* padded = (const float*)d_in[0];
    const int*   seq    = (const int*)  d_in[1];
    const float* eWih   = (const float*)d_in[2];
    const float* eWhh   = (const float*)d_in[3];
    const float* eb     = (const float*)d_in[4];
    const float* elW    = (const float*)d_in[5];
    const float* elb    = (const float*)d_in[6];
    const float* dlW    = (const float*)d_in[7];
    const float* dlb    = (const float*)d_in[8];
    const float* dWih   = (const float*)d_in[9];
    const float* dWhh   = (const float*)d_in[10];
    const float* db     = (const float*)d_in[11];
    const float* outW   = (const float*)d_in[12];
    const float* outb   = (const float*)d_in[13];
    float* out = (float*)d_out;

    float* ws    = (float*)d_ws;
    float* h_enc = ws;
    float* c_enc = ws + (long)B * H;
    float* hd    = ws + 2L * B * H;
    float* y0c   = ws + 3L * B * H;
    float* acc2  = ws + 3L * B * H + B;

    float* out_pad = out + 1;
    float* out_y   = out + 1 + (long)B * T;
    float* out_hz  = out + 1 + 2L * (long)B * T;

    hipMemcpyAsync(out_pad, padded, (long)B * T * sizeof(float),
                   hipMemcpyDeviceToDevice, stream);
    hipMemsetAsync(acc2, 0, 2 * sizeof(float), stream);

    enc_kernel<<<NB, NTHREADS, 0, stream>>>(padded, seq, eWih, eWhh, eb, h_enc, c_enc);
    mid_kernel<<<B / 256, 256, 0, stream>>>(h_enc, elW, elb, dlW, dlb, outW, outb,
                                            out_hz, hd, y0c);
    dec_kernel<<<NB, NTHREADS, 0, stream>>>(hd, c_enc, dWih, dWhh, db, outW, outb, y0c, out_y);
    loss_kernel<<<1024, 256, 0, stream>>>(padded, out_y, seq, acc2);
    fin_kernel<<<1, 1, 0, stream>>>(acc2, out);
}